// Round 1
// baseline (522.035 us; speedup 1.0000x reference)
//
#include <hip/hip_runtime.h>

// Fused causal self-attention block, MI355X gfx950.
// B=2, T=2048, E=1024, H=16, D=64.  All MFMA in bf16 (mfma_f32_16x16x32_bf16),
// fp32 accumulation. Verified fragment layouts (learn_hip m89/m91):
//   A[m = lane&15][k = (lane>>4)*8 + j]   (8 bf16 = 16B contiguous)
//   B[k = (lane>>4)*8 + j][n = lane&15]
//   C/D[row = (lane>>4)*4 + r][col = lane&15]

typedef unsigned short u16;
typedef __bf16 bf8 __attribute__((ext_vector_type(8)));
typedef float f32x4 __attribute__((ext_vector_type(4)));

struct __align__(16) u16x8 { u16 v[8]; };

__device__ __forceinline__ u16 f2b(float f) {
    union { float f; unsigned u; } x{f};
    unsigned r = x.u + 0x7fffu + ((x.u >> 16) & 1u);   // RNE
    return (u16)(r >> 16);
}

__device__ __forceinline__ f32x4 mfma16(bf8 a, bf8 b, f32x4 c) {
    return __builtin_amdgcn_mfma_f32_16x16x32_bf16(a, b, c, 0, 0, 0);
}

// ---------------- convert x fp32 -> bf16 (same layout) ----------------
__global__ __launch_bounds__(256) void k_cvt(const float* __restrict__ in,
                                             u16* __restrict__ out, int n4) {
    int i = blockIdx.x * 256 + threadIdx.x;
    if (i >= n4) return;
    float4 v = ((const float4*)in)[i];
    ushort4 o;
    o.x = f2b(v.x); o.y = f2b(v.y); o.z = f2b(v.z); o.w = f2b(v.w);
    ((ushort4*)out)[i] = o;
}

// ------------- transpose+convert W [K][N] fp32 -> Wt [N][K] bf16 -------------
__global__ __launch_bounds__(256) void k_tr(const float* __restrict__ in,
                                            u16* __restrict__ out, int K, int N) {
    __shared__ float tile[64][65];
    int k0 = blockIdx.x * 64, n0 = blockIdx.y * 64;
    int t = threadIdx.x, c = t & 63, r0 = t >> 6;
#pragma unroll
    for (int i = 0; i < 16; ++i) {
        int r = r0 + i * 4;
        tile[r][c] = in[(size_t)(k0 + r) * N + n0 + c];
    }
    __syncthreads();
#pragma unroll
    for (int i = 0; i < 16; ++i) {
        int r = r0 + i * 4;
        out[(size_t)(n0 + r) * K + k0 + c] = f2b(tile[c][r]);
    }
}

// ---------------- QKV GEMM: [4096,1024]bf16 @ Wt[3072,1024] + bias ----------------
// epilogue scatters into Q/K/V [B*H][T][D] bf16
__global__ __launch_bounds__(256) void k_qkv(const u16* __restrict__ Xb,
                                             const u16* __restrict__ WtA,
                                             const float* __restrict__ ba,
                                             u16* __restrict__ Qb,
                                             u16* __restrict__ Kb,
                                             u16* __restrict__ Vb) {
    int w = threadIdx.x >> 6, lane = threadIdx.x & 63;
    int l16 = lane & 15, quad = lane >> 4;
    int m0 = blockIdx.x * 64 + w * 16;
    int n0 = blockIdx.y * 64;
    f32x4 acc[4];
#pragma unroll
    for (int s = 0; s < 4; ++s)
#pragma unroll
        for (int r = 0; r < 4; ++r) acc[s][r] = 0.f;

    const u16* ap  = Xb  + (size_t)(m0 + l16) * 1024 + quad * 8;
    const u16* bp0 = WtA + (size_t)(n0 + l16) * 1024 + quad * 8;
    for (int k = 0; k < 1024; k += 32) {
        bf8 a = *(const bf8*)(ap + k);
#pragma unroll
        for (int s = 0; s < 4; ++s) {
            bf8 b = *(const bf8*)(bp0 + (size_t)s * 16 * 1024 + k);
            acc[s] = mfma16(a, b, acc[s]);
        }
    }
    int sel = n0 >> 10;                       // 0:Q 1:K 2:V (uniform per block)
    u16* dst = sel == 0 ? Qb : (sel == 1 ? Kb : Vb);
    int h = (n0 & 1023) >> 6;                 // uniform per block
#pragma unroll
    for (int s = 0; s < 4; ++s) {
        int n = n0 + s * 16 + l16;
        float bias = ba[n];
        int d = s * 16 + l16;                 // n0 % 64 == 0
#pragma unroll
        for (int r = 0; r < 4; ++r) {
            int m = m0 + quad * 4 + r;
            int bb = m >> 11, t = m & 2047;
            dst[(((size_t)(bb * 16 + h)) * 2048 + t) * 64 + d] = f2b(acc[s][r] + bias);
        }
    }
}

// ---------------- flash attention (causal), 1 block = 64 Q rows of one (b,h) ----------------
__global__ __launch_bounds__(256) void k_attn(const u16* __restrict__ Qb,
                                              const u16* __restrict__ Kb,
                                              const u16* __restrict__ Vb,
                                              u16* __restrict__ AO) {
    int qt = blockIdx.x, bh = blockIdx.y;
    int tid = threadIdx.x;
    int w = tid >> 6, lane = tid & 63, l16 = lane & 15, quad = lane >> 4;
    const size_t hoff = (size_t)bh * 2048 * 64;
    const u16* Qh = Qb + hoff;
    const u16* Kh = Kb + hoff;
    const u16* Vh = Vb + hoff;
    int q0 = qt * 64;
    int qrow = q0 + w * 16;

    __shared__ u16 Vt[64][72];       // V transposed: Vt[d][key], pad->144B rows
    __shared__ u16 P[4][16][72];     // per-wave P in A-operand-friendly layout

    bf8 qf0 = *(const bf8*)(Qh + (size_t)(qrow + l16) * 64 + quad * 8);
    bf8 qf1 = *(const bf8*)(Qh + (size_t)(qrow + l16) * 64 + 32 + quad * 8);

    float m_i[4], l_i[4];
    f32x4 o_acc[4];
#pragma unroll
    for (int r = 0; r < 4; ++r) { m_i[r] = -1e30f; l_i[r] = 0.f; }
#pragma unroll
    for (int dt = 0; dt < 4; ++dt)
#pragma unroll
        for (int r = 0; r < 4; ++r) o_acc[dt][r] = 0.f;

    int key_v = tid & 63;            // V staging: lane -> key (LDS-conflict-friendly)
    int dgrp8 = (tid >> 6) * 8;

    for (int kt = 0; kt <= qt; ++kt) {
        int kbase = kt * 64;
        __syncthreads();             // protect Vt reads of previous iter
        {
            const u16* vsrc = Vh + (size_t)(kbase + key_v) * 64 + dgrp8;
            u16x8 v0 = *(const u16x8*)(vsrc);
            u16x8 v1 = *(const u16x8*)(vsrc + 32);
#pragma unroll
            for (int j = 0; j < 8; ++j) Vt[dgrp8 + j][key_v] = v0.v[j];
#pragma unroll
            for (int j = 0; j < 8; ++j) Vt[dgrp8 + 32 + j][key_v] = v1.v[j];
        }
        __syncthreads();

        // S = Q K^T : rows q=quad*4+r, cols key=sub*16+l16
        f32x4 s_acc[4];
#pragma unroll
        for (int s = 0; s < 4; ++s)
#pragma unroll
            for (int r = 0; r < 4; ++r) s_acc[s][r] = 0.f;
        const u16* kp = Kh + (size_t)(kbase + l16) * 64 + quad * 8;
#pragma unroll
        for (int sub = 0; sub < 4; ++sub) {
            bf8 kf0 = *(const bf8*)(kp + (size_t)sub * 16 * 64);
            bf8 kf1 = *(const bf8*)(kp + (size_t)sub * 16 * 64 + 32);
            s_acc[sub] = mfma16(qf0, kf0, s_acc[sub]);
            s_acc[sub] = mfma16(qf1, kf1, s_acc[sub]);
        }

        // online softmax per row (row = quad*4+r, 16 lanes of quad share it)
        float alpha[4];
#pragma unroll
        for (int r = 0; r < 4; ++r) {
            int qg = qrow + quad * 4 + r;
            float sv[4], sm = -1e30f;
#pragma unroll
            for (int sub = 0; sub < 4; ++sub) {
                int key = kbase + sub * 16 + l16;
                float s = s_acc[sub][r] * 0.125f;     // 1/sqrt(64)
                s = (key <= qg) ? s : -1e30f;         // causal mask
                sv[sub] = s;
                sm = fmaxf(sm, s);
            }
            sm = fmaxf(sm, __shfl_xor(sm, 1, 64));
            sm = fmaxf(sm, __shfl_xor(sm, 2, 64));
            sm = fmaxf(sm, __shfl_xor(sm, 4, 64));
            sm = fmaxf(sm, __shfl_xor(sm, 8, 64));
            float mn = fmaxf(m_i[r], sm);
            float al = __expf(m_i[r] - mn);
            float rs = 0.f;
#pragma unroll
            for (int sub = 0; sub < 4; ++sub) {
                float p = __expf(sv[sub] - mn);
                rs += p;
                P[w][quad * 4 + r][sub * 16 + l16] = f2b(p);
            }
            rs += __shfl_xor(rs, 1, 64);
            rs += __shfl_xor(rs, 2, 64);
            rs += __shfl_xor(rs, 4, 64);
            rs += __shfl_xor(rs, 8, 64);
            l_i[r] = l_i[r] * al + rs;
            m_i[r] = mn;
            alpha[r] = al;
        }
        asm volatile("s_waitcnt lgkmcnt(0)" ::: "memory");  // P writes visible wave-wide

        // rescale O (O rows = quad*4+r: same mapping as alpha)
#pragma unroll
        for (int dt = 0; dt < 4; ++dt)
#pragma unroll
            for (int r = 0; r < 4; ++r) o_acc[dt][r] *= alpha[r];

        // O += P @ V  (A=P from LDS, B=V^T rows from Vt)
#pragma unroll
        for (int ks = 0; ks < 2; ++ks) {
            bf8 pf = *(const bf8*)(&P[w][l16][ks * 32 + quad * 8]);
#pragma unroll
            for (int dt = 0; dt < 4; ++dt) {
                bf8 vf = *(const bf8*)(&Vt[dt * 16 + l16][ks * 32 + quad * 8]);
                o_acc[dt] = mfma16(pf, vf, o_acc[dt]);
            }
        }
    }

    // epilogue: AO[b*2048+q][h*64+d] bf16  (proj-GEMM A layout)
    int b = bh >> 4, h = bh & 15;
#pragma unroll
    for (int dt = 0; dt < 4; ++dt)
#pragma unroll
        for (int r = 0; r < 4; ++r) {
            int qg = qrow + quad * 4 + r;
            size_t row = (size_t)b * 2048 + qg;
            AO[row * 1024 + h * 64 + dt * 16 + l16] = f2b(o_acc[dt][r] / l_i[r]);
        }
}

// ---------------- proj GEMM: AO[4096,1024]bf16 @ WtP[1024,1024] + bias -> fp32 out ----------------
__global__ __launch_bounds__(256) void k_proj(const u16* __restrict__ AO,
                                              const u16* __restrict__ WtP,
                                              const float* __restrict__ bp,
                                              float* __restrict__ out) {
    int w = threadIdx.x >> 6, lane = threadIdx.x & 63;
    int l16 = lane & 15, quad = lane >> 4;
    int m0 = blockIdx.x * 64 + w * 16;
    int n0 = blockIdx.y * 64;
    f32x4 acc[4];
#pragma unroll
    for (int s = 0; s < 4; ++s)
#pragma unroll
        for (int r = 0; r < 4; ++r) acc[s][r] = 0.f;

    const u16* ap  = AO  + (size_t)(m0 + l16) * 1024 + quad * 8;
    const u16* bp0 = WtP + (size_t)(n0 + l16) * 1024 + quad * 8;
    for (int k = 0; k < 1024; k += 32) {
        bf8 a = *(const bf8*)(ap + k);
#pragma unroll
        for (int s = 0; s < 4; ++s) {
            bf8 b = *(const bf8*)(bp0 + (size_t)s * 16 * 1024 + k);
            acc[s] = mfma16(a, b, acc[s]);
        }
    }
#pragma unroll
    for (int s = 0; s < 4; ++s) {
        int n = n0 + s * 16 + l16;
        float bias = bp[n];
#pragma unroll
        for (int r = 0; r < 4; ++r) {
            int m = m0 + quad * 4 + r;
            out[(size_t)m * 1024 + n] = acc[s][r] + bias;
        }
    }
}

extern "C" void kernel_launch(void* const* d_in, const int* in_sizes, int n_in,
                              void* d_out, int out_size, void* d_ws, size_t ws_size,
                              hipStream_t stream) {
    const float* x  = (const float*)d_in[0];
    const float* Wa = (const float*)d_in[1];
    const float* ba = (const float*)d_in[2];
    const float* Wp = (const float*)d_in[3];
    const float* bp = (const float*)d_in[4];
    float* out = (float*)d_out;

    char* ws = (char*)d_ws;
    const size_t MB = 1024 * 1024;
    u16* Xb  = (u16*)(ws);             // 8 MB  x as bf16   (reused as AO later)
    u16* WtA = (u16*)(ws + 8  * MB);   // 6 MB  W_attn^T bf16
    u16* WtP = (u16*)(ws + 14 * MB);   // 2 MB  W_proj^T bf16
    u16* Qb  = (u16*)(ws + 16 * MB);   // 8 MB  [B*H][T][D]
    u16* Kb  = (u16*)(ws + 24 * MB);   // 8 MB
    u16* Vb  = (u16*)(ws + 32 * MB);   // 8 MB
    u16* AO  = Xb;                     // alias: Xb dead after k_qkv (stream-ordered)

    k_cvt <<<dim3(4096),    dim3(256), 0, stream>>>(x, Xb, 1048576);
    k_tr  <<<dim3(16, 48),  dim3(256), 0, stream>>>(Wa, WtA, 1024, 3072);
    k_tr  <<<dim3(16, 16),  dim3(256), 0, stream>>>(Wp, WtP, 1024, 1024);
    k_qkv <<<dim3(64, 48),  dim3(256), 0, stream>>>(Xb, WtA, ba, Qb, Kb, Vb);
    k_attn<<<dim3(32, 32),  dim3(256), 0, stream>>>(Qb, Kb, Vb, AO);
    k_proj<<<dim3(64, 16),  dim3(256), 0, stream>>>(AO, WtP, bp, out);
}

// Round 2
// 302.645 us; speedup vs baseline: 1.7249x; 1.7249x over previous
//
#include <hip/hip_runtime.h>

// Fused causal self-attention block, MI355X gfx950.
// B=2, T=2048, E=1024, H=16, D=64.  All MFMA in bf16 (mfma_f32_16x16x32_bf16),
// fp32 accumulation. Verified fragment layouts (learn_hip m89/m91):
//   A[m = lane&15][k = (lane>>4)*8 + j]   (8 bf16 = 16B contiguous)
//   B[k = (lane>>4)*8 + j][n = lane&15]
//   C/D[row = (lane>>4)*4 + r][col = lane&15]
// GEMMs use the m97 structure: 128x128 tile, BK=32, global_load_lds width=16,
// 4 waves x (4x4 16x16 tiles), ds_read_b128 fragments.

typedef unsigned short u16;
typedef __bf16 bf8 __attribute__((ext_vector_type(8)));
typedef float f32x4 __attribute__((ext_vector_type(4)));

struct __align__(16) u16x8 { u16 v[8]; };

__device__ __forceinline__ u16 f2b(float f) {
    union { float f; unsigned u; } x{f};
    unsigned r = x.u + 0x7fffu + ((x.u >> 16) & 1u);   // RNE
    return (u16)(r >> 16);
}

__device__ __forceinline__ f32x4 mfma16(bf8 a, bf8 b, f32x4 c) {
    return __builtin_amdgcn_mfma_f32_16x16x32_bf16(a, b, c, 0, 0, 0);
}

// async global->LDS, 16B per lane. LDS dest must be wave-uniform base + lane*16.
__device__ __forceinline__ void gload_lds16(const u16* g, u16* l) {
    __builtin_amdgcn_global_load_lds(
        (__attribute__((address_space(1))) void*)(g),
        (__attribute__((address_space(3))) void*)(l), 16, 0, 0);
}

// ---------------- convert x fp32 -> bf16 (same layout) ----------------
__global__ __launch_bounds__(256) void k_cvt(const float* __restrict__ in,
                                             u16* __restrict__ out, int n4) {
    int i = blockIdx.x * 256 + threadIdx.x;
    if (i >= n4) return;
    float4 v = ((const float4*)in)[i];
    ushort4 o;
    o.x = f2b(v.x); o.y = f2b(v.y); o.z = f2b(v.z); o.w = f2b(v.w);
    ((ushort4*)out)[i] = o;
}

// ------------- transpose+convert W [K][N] fp32 -> Wt [N][K] bf16 -------------
__global__ __launch_bounds__(256) void k_tr(const float* __restrict__ in,
                                            u16* __restrict__ out, int K, int N) {
    __shared__ float tile[64][65];
    int k0 = blockIdx.x * 64, n0 = blockIdx.y * 64;
    int t = threadIdx.x, c = t & 63, r0 = t >> 6;
#pragma unroll
    for (int i = 0; i < 16; ++i) {
        int r = r0 + i * 4;
        tile[r][c] = in[(size_t)(k0 + r) * N + n0 + c];
    }
    __syncthreads();
#pragma unroll
    for (int i = 0; i < 16; ++i) {
        int r = r0 + i * 4;
        out[(size_t)(n0 + r) * K + k0 + c] = f2b(tile[c][r]);
    }
}

// =====================================================================
// m97-style GEMM core: C[128x128] per block, A[M][1024] @ Wt[N][1024]^T.
// Produces acc[mi][ni] (f32x4 each); epilogue differs per kernel.
// =====================================================================
#define GEMM_CORE(Aptr, Bptr)                                                  \
    int tid = threadIdx.x;                                                     \
    int w = tid >> 6, lane = tid & 63, l16 = lane & 15, quad = lane >> 4;      \
    int m0 = blockIdx.x * 128, n0 = blockIdx.y * 128;                          \
    int wr = (w >> 1) * 64, wc = (w & 1) * 64;                                 \
    __shared__ u16 As[128 * 32];                                               \
    __shared__ u16 Bs[128 * 32];                                               \
    f32x4 acc[4][4];                                                           \
    _Pragma("unroll") for (int mi = 0; mi < 4; ++mi)                           \
        _Pragma("unroll") for (int ni = 0; ni < 4; ++ni)                       \
            _Pragma("unroll") for (int r = 0; r < 4; ++r) acc[mi][ni][r] = 0.f;\
    int srow = tid >> 2;                                                       \
    int scol = (tid & 3) * 8;                                                  \
    const u16* gA = Aptr + (size_t)(m0 + srow) * 1024 + scol;                  \
    const u16* gB = Bptr + (size_t)(n0 + srow) * 1024 + scol;                  \
    u16* lA0 = As + tid * 8;  u16* lA1 = As + (256 + tid) * 8;                 \
    u16* lB0 = Bs + tid * 8;  u16* lB1 = Bs + (256 + tid) * 8;                 \
    for (int k0 = 0; k0 < 1024; k0 += 32) {                                    \
        gload_lds16(gA, lA0);                                                  \
        gload_lds16(gA + 64 * 1024, lA1);                                      \
        gload_lds16(gB, lB0);                                                  \
        gload_lds16(gB + 64 * 1024, lB1);                                      \
        gA += 32; gB += 32;                                                    \
        __syncthreads();                                                       \
        bf8 af[4], bf[4];                                                      \
        _Pragma("unroll") for (int mi = 0; mi < 4; ++mi)                       \
            af[mi] = *(const bf8*)(As + (wr + mi * 16 + l16) * 32 + quad * 8); \
        _Pragma("unroll") for (int ni = 0; ni < 4; ++ni)                       \
            bf[ni] = *(const bf8*)(Bs + (wc + ni * 16 + l16) * 32 + quad * 8); \
        _Pragma("unroll") for (int mi = 0; mi < 4; ++mi)                       \
            _Pragma("unroll") for (int ni = 0; ni < 4; ++ni)                   \
                acc[mi][ni] = mfma16(af[mi], bf[ni], acc[mi][ni]);             \
        __syncthreads();                                                       \
    }

// ---------------- QKV GEMM: [4096,1024] @ Wt[3072,1024] + bias ----------------
// epilogue scatters into Q/K/V [B*H][T][D] bf16
__global__ __launch_bounds__(256) void k_qkv(const u16* __restrict__ Xb,
                                             const u16* __restrict__ WtA,
                                             const float* __restrict__ ba,
                                             u16* __restrict__ Qb,
                                             u16* __restrict__ Kb,
                                             u16* __restrict__ Vb) {
    GEMM_CORE(Xb, WtA)
    int sel = n0 >> 10;                       // 0:Q 1:K 2:V (uniform: n0 % 128 == 0)
    u16* dst = sel == 0 ? Qb : (sel == 1 ? Kb : Vb);
#pragma unroll
    for (int ni = 0; ni < 4; ++ni) {
        int n = n0 + wc + ni * 16 + l16;
        float bias = ba[n];
        int h = (n & 1023) >> 6;
        int d = n & 63;
#pragma unroll
        for (int mi = 0; mi < 4; ++mi)
#pragma unroll
            for (int r = 0; r < 4; ++r) {
                int m = m0 + wr + mi * 16 + quad * 4 + r;
                int bb = m >> 11, tt = m & 2047;
                dst[(((size_t)(bb * 16 + h)) * 2048 + tt) * 64 + d] =
                    f2b(acc[mi][ni][r] + bias);
            }
    }
}

// ---------------- proj GEMM: AO[4096,1024] @ WtP[1024,1024] + bias -> fp32 ----------------
__global__ __launch_bounds__(256) void k_proj(const u16* __restrict__ AO,
                                              const u16* __restrict__ WtP,
                                              const float* __restrict__ bp,
                                              float* __restrict__ out) {
    GEMM_CORE(AO, WtP)
#pragma unroll
    for (int ni = 0; ni < 4; ++ni) {
        int n = n0 + wc + ni * 16 + l16;
        float bias = bp[n];
#pragma unroll
        for (int mi = 0; mi < 4; ++mi)
#pragma unroll
            for (int r = 0; r < 4; ++r) {
                int m = m0 + wr + mi * 16 + quad * 4 + r;
                out[(size_t)m * 1024 + n] = acc[mi][ni][r] + bias;
            }
    }
}

// ---------------- flash attention (causal), 1 block = 64 Q rows of one (b,h) ----------------
__global__ __launch_bounds__(256) void k_attn(const u16* __restrict__ Qb,
                                              const u16* __restrict__ Kb,
                                              const u16* __restrict__ Vb,
                                              u16* __restrict__ AO) {
    int qt = blockIdx.x, bh = blockIdx.y;
    int tid = threadIdx.x;
    int w = tid >> 6, lane = tid & 63, l16 = lane & 15, quad = lane >> 4;
    const size_t hoff = (size_t)bh * 2048 * 64;
    const u16* Qh = Qb + hoff;
    const u16* Kh = Kb + hoff;
    const u16* Vh = Vb + hoff;
    int q0 = qt * 64;
    int qrow = q0 + w * 16;

    __shared__ u16 Vt[64][72];       // V transposed: Vt[d][key], pad->144B rows
    __shared__ u16 P[4][16][72];     // per-wave P in A-operand-friendly layout

    bf8 qf0 = *(const bf8*)(Qh + (size_t)(qrow + l16) * 64 + quad * 8);
    bf8 qf1 = *(const bf8*)(Qh + (size_t)(qrow + l16) * 64 + 32 + quad * 8);

    float m_i[4], l_i[4];
    f32x4 o_acc[4];
#pragma unroll
    for (int r = 0; r < 4; ++r) { m_i[r] = -1e30f; l_i[r] = 0.f; }
#pragma unroll
    for (int dt = 0; dt < 4; ++dt)
#pragma unroll
        for (int r = 0; r < 4; ++r) o_acc[dt][r] = 0.f;

    int key_v = tid & 63;            // V staging: lane -> key
    int dgrp8 = (tid >> 6) * 8;

    for (int kt = 0; kt <= qt; ++kt) {
        int kbase = kt * 64;
        __syncthreads();             // protect Vt reads of previous iter
        {
            const u16* vsrc = Vh + (size_t)(kbase + key_v) * 64 + dgrp8;
            u16x8 v0 = *(const u16x8*)(vsrc);
            u16x8 v1 = *(const u16x8*)(vsrc + 32);
#pragma unroll
            for (int j = 0; j < 8; ++j) Vt[dgrp8 + j][key_v] = v0.v[j];
#pragma unroll
            for (int j = 0; j < 8; ++j) Vt[dgrp8 + 32 + j][key_v] = v1.v[j];
        }
        __syncthreads();

        // S = Q K^T : rows q=quad*4+r, cols key=sub*16+l16
        f32x4 s_acc[4];
#pragma unroll
        for (int s = 0; s < 4; ++s)
#pragma unroll
            for (int r = 0; r < 4; ++r) s_acc[s][r] = 0.f;
        const u16* kp = Kh + (size_t)(kbase + l16) * 64 + quad * 8;
#pragma unroll
        for (int sub = 0; sub < 4; ++sub) {
            bf8 kf0 = *(const bf8*)(kp + (size_t)sub * 16 * 64);
            bf8 kf1 = *(const bf8*)(kp + (size_t)sub * 16 * 64 + 32);
            s_acc[sub] = mfma16(qf0, kf0, s_acc[sub]);
            s_acc[sub] = mfma16(qf1, kf1, s_acc[sub]);
        }

        // online softmax per row (row = quad*4+r, 16 lanes of quad share it)
        float alpha[4];
#pragma unroll
        for (int r = 0; r < 4; ++r) {
            int qg = qrow + quad * 4 + r;
            float sv[4], sm = -1e30f;
#pragma unroll
            for (int sub = 0; sub < 4; ++sub) {
                int key = kbase + sub * 16 + l16;
                float s = s_acc[sub][r] * 0.125f;     // 1/sqrt(64)
                s = (key <= qg) ? s : -1e30f;         // causal mask
                sv[sub] = s;
                sm = fmaxf(sm, s);
            }
            sm = fmaxf(sm, __shfl_xor(sm, 1, 64));
            sm = fmaxf(sm, __shfl_xor(sm, 2, 64));
            sm = fmaxf(sm, __shfl_xor(sm, 4, 64));
            sm = fmaxf(sm, __shfl_xor(sm, 8, 64));
            float mn = fmaxf(m_i[r], sm);
            float al = __expf(m_i[r] - mn);
            float rs = 0.f;
#pragma unroll
            for (int sub = 0; sub < 4; ++sub) {
                float p = __expf(sv[sub] - mn);
                rs += p;
                P[w][quad * 4 + r][sub * 16 + l16] = f2b(p);
            }
            rs += __shfl_xor(rs, 1, 64);
            rs += __shfl_xor(rs, 2, 64);
            rs += __shfl_xor(rs, 4, 64);
            rs += __shfl_xor(rs, 8, 64);
            l_i[r] = l_i[r] * al + rs;
            m_i[r] = mn;
            alpha[r] = al;
        }
        asm volatile("s_waitcnt lgkmcnt(0)" ::: "memory");  // P writes visible wave-wide

        // rescale O (O rows = quad*4+r: same mapping as alpha)
#pragma unroll
        for (int dt = 0; dt < 4; ++dt)
#pragma unroll
            for (int r = 0; r < 4; ++r) o_acc[dt][r] *= alpha[r];

        // O += P @ V  (A=P from LDS, B=V^T rows from Vt)
#pragma unroll
        for (int ks = 0; ks < 2; ++ks) {
            bf8 pf = *(const bf8*)(&P[w][l16][ks * 32 + quad * 8]);
#pragma unroll
            for (int dt = 0; dt < 4; ++dt) {
                bf8 vf = *(const bf8*)(&Vt[dt * 16 + l16][ks * 32 + quad * 8]);
                o_acc[dt] = mfma16(pf, vf, o_acc[dt]);
            }
        }
    }

    // epilogue: AO[b*2048+q][h*64+d] bf16  (proj-GEMM A layout)
    int b = bh >> 4, h = bh & 15;
#pragma unroll
    for (int dt = 0; dt < 4; ++dt)
#pragma unroll
        for (int r = 0; r < 4; ++r) {
            int qg = qrow + quad * 4 + r;
            size_t row = (size_t)b * 2048 + qg;
            AO[row * 1024 + h * 64 + dt * 16 + l16] = f2b(o_acc[dt][r] / l_i[r]);
        }
}

extern "C" void kernel_launch(void* const* d_in, const int* in_sizes, int n_in,
                              void* d_out, int out_size, void* d_ws, size_t ws_size,
                              hipStream_t stream) {
    const float* x  = (const float*)d_in[0];
    const float* Wa = (const float*)d_in[1];
    const float* ba = (const float*)d_in[2];
    const float* Wp = (const float*)d_in[3];
    const float* bp = (const float*)d_in[4];
    float* out = (float*)d_out;

    char* ws = (char*)d_ws;
    const size_t MB = 1024 * 1024;
    u16* Xb  = (u16*)(ws);             // 8 MB  x as bf16   (reused as AO later)
    u16* WtA = (u16*)(ws + 8  * MB);   // 6 MB  W_attn^T bf16
    u16* WtP = (u16*)(ws + 14 * MB);   // 2 MB  W_proj^T bf16
    u16* Qb  = (u16*)(ws + 16 * MB);   // 8 MB  [B*H][T][D]
    u16* Kb  = (u16*)(ws + 24 * MB);   // 8 MB
    u16* Vb  = (u16*)(ws + 32 * MB);   // 8 MB
    u16* AO  = Xb;                     // alias: Xb dead after k_qkv (stream-ordered)

    k_cvt <<<dim3(4096),    dim3(256), 0, stream>>>(x, Xb, 1048576);
    k_tr  <<<dim3(16, 48),  dim3(256), 0, stream>>>(Wa, WtA, 1024, 3072);
    k_tr  <<<dim3(16, 16),  dim3(256), 0, stream>>>(Wp, WtP, 1024, 1024);
    k_qkv <<<dim3(32, 24),  dim3(256), 0, stream>>>(Xb, WtA, ba, Qb, Kb, Vb);
    k_attn<<<dim3(32, 32),  dim3(256), 0, stream>>>(Qb, Kb, Vb, AO);
    k_proj<<<dim3(32, 8),   dim3(256), 0, stream>>>(AO, WtP, bp, out);
}